// Round 7
// baseline (32.498 us; speedup 1.0000x reference)
//
#include <hip/hip_runtime.h>

// Problem constants
#define B_       128
#define N_WAY    5
#define QUERY    15
#define NUM_SLOT 32
#define H_       256
#define NS       (B_ * N_WAY)            // 640 support samples
#define NQ       (B_ * N_WAY * QUERY)    // 9600 query samples
#define ROW      (NUM_SLOT * H_)         // 8192 floats per sample
#define SPB      (N_WAY * QUERY)         // 75 query samples per batch
#define RPB      (N_WAY * NUM_SLOT)      // 160 support rows per batch
#define NBLK     (2 * B_)                // 256 blocks, 2 per batch (1 per CU)
#define TAG      0x13572468u

typedef unsigned long long ull;
union PU { ull u; float2 f; };

__device__ __forceinline__ float wave_reduce(float v) {
    for (int m = 32; m > 0; m >>= 1) v += __shfl_xor(v, m, 64);
    return v;
}

// Single kernel: 2 blocks per batch, 16 waves each (full chip).
//  a) wave-reduce the batch's 160 contiguous support rows -> LDS scores
//  b) wave 0: butterfly argmax greedy select (max,min-idx == stable first-max)
//  c) waves 0-4 normalize selected rows into LDS protos (+ exact p2)
//  d) each wave: its share of the block's 38/37 query samples; joint s2/dt
//     shuffle reduce (identical tree/bits to R5/R6), softmax-CE + argmin
//  e) block partial -> device-scope atomic publish + TAG flag;
//     block 0 spins on all flags, reduces 256 partials in fixed order, writes out.
//     Replay-safe: partials are bit-identical every call, so stale TAGs are benign.
__global__ __launch_bounds__(1024)
void k_all(const float* __restrict__ out_f, const int* __restrict__ labels_q,
           const float* __restrict__ att_loss, ull* __restrict__ part,
           unsigned* __restrict__ flags, float* __restrict__ out) {
    int blk = blockIdx.x, b = blk >> 1, half = blk & 1;
    int t = threadIdx.x, wid = t >> 6, lane = t & 63;

    __shared__ float sc[RPB];
    __shared__ int ssel[N_WAY];
    __shared__ __align__(16) float pl[N_WAY][H_];   // normalized protos (5 KB)
    __shared__ float p2s[N_WAY];
    __shared__ float s_n[16], s_c[16];
    __shared__ float ra[4], rc[4];

    // a) row means: rows contiguous at out_f[b*160 + i][:]
    const float* base = out_f + (size_t)b * RPB * H_;
    for (int i = wid; i < RPB; i += 32) {           // 16 waves x (2 rows x 5 iters)
        float4 v0 = ((const float4*)(base + (size_t)i * H_))[lane];
        float4 v1 = ((const float4*)(base + (size_t)(i + 16) * H_))[lane];
        float s0 = wave_reduce(v0.x + v0.y + v0.z + v0.w);
        float s1 = wave_reduce(v1.x + v1.y + v1.z + v1.w);
        if (lane == 0) { sc[i] = s0 * (1.0f / H_); sc[i + 16] = s1 * (1.0f / H_); }
    }
    __syncthreads();

    // b) greedy select, wave-parallel: butterfly (max, min-index) == first-max scan
    if (t < 64) {
        unsigned used = 0u;
        for (int j = 0; j < N_WAY; ++j) {
            float v = (lane < NUM_SLOT && !((used >> lane) & 1u))
                        ? sc[j * NUM_SLOT + lane] : -INFINITY;
            int idx = (lane < NUM_SLOT) ? lane : 63;
            for (int m = 32; m > 0; m >>= 1) {
                float v2 = __shfl_xor(v, m, 64);
                int  i2 = __shfl_xor(idx, m, 64);
                if (v2 > v || (v2 == v && i2 < idx)) { v = v2; idx = i2; }
            }
            used |= 1u << idx;                       // all lanes converged
            if (lane == 0) ssel[j] = idx;
        }
    }
    __syncthreads();

    // c) normalize selected rows -> LDS protos; p2 via same reduce tree
    if (wid < N_WAY) {
        int k = wid;
        float4 v = ((const float4*)(base + ((size_t)k * NUM_SLOT + ssel[k]) * H_))[lane];
        float s2 = wave_reduce(v.x*v.x + v.y*v.y + v.z*v.z + v.w*v.w);
        float inv = 1.0f / fmaxf(sqrtf(s2), 1e-12f);
        float4 nv = make_float4(v.x*inv, v.y*inv, v.z*inv, v.w*inv);
        *(float4*)&pl[k][lane * 4] = nv;
        float p2 = wave_reduce(nv.x*nv.x + nv.y*nv.y + nv.z*nv.z + nv.w*nv.w);
        if (lane == 0) p2s[k] = p2;
    }
    __syncthreads();

    // d) query samples: half 0 -> [0,38), half 1 -> [38,75)
    int sBeg = half ? 38 : 0;
    int sEnd = half ? SPB : 38;
    float accn = 0.0f, accc = 0.0f;
    for (int s = sBeg + wid; s < sEnd; s += 16) {
        int id = b * SPB + s;
        const float* qrow = out_f + (size_t)(NS + id) * ROW;
        float4 qv[N_WAY];
        #pragma unroll
        for (int k = 0; k < N_WAY; ++k)             // issue all 5 loads up front
            qv[k] = ((const float4*)(qrow + (size_t)ssel[k] * H_))[lane];
        float diffs[N_WAY];
        #pragma unroll
        for (int k = 0; k < N_WAY; ++k) {
            float4 pv = *(const float4*)&pl[k][lane * 4];
            float s2 = qv[k].x*qv[k].x + qv[k].y*qv[k].y + qv[k].z*qv[k].z + qv[k].w*qv[k].w;
            float dt = qv[k].x*pv.x + qv[k].y*pv.y + qv[k].z*pv.z + qv[k].w*pv.w;
            for (int m = 32; m > 0; m >>= 1) {
                s2 += __shfl_xor(s2, m, 64);
                dt += __shfl_xor(dt, m, 64);
            }
            float inv = 1.0f / fmaxf(sqrtf(s2), 1e-12f);
            diffs[k] = s2 * inv * inv - 2.0f * dt * inv + p2s[k];
        }
        if (lane == 0) {
            int l = labels_q[id];                   // label index == flat sample index
            float mn = diffs[0]; int am = 0;
            #pragma unroll
            for (int k = 1; k < N_WAY; ++k)
                if (diffs[k] < mn) { mn = diffs[k]; am = k; }  // first min == argmax logits
            float se = 0.0f;
            #pragma unroll
            for (int k = 0; k < N_WAY; ++k) se += expf(mn - diffs[k]);
            accn += diffs[l] - mn + logf(se);
            accc += (am == l) ? 1.0f : 0.0f;
        }
    }
    if (lane == 0) { s_n[wid] = accn; s_c[wid] = accc; }
    __syncthreads();

    // e) publish block partial (device-scope), then block 0 finalizes
    if (t == 0) {
        float a = 0.0f, c = 0.0f;
        #pragma unroll
        for (int i = 0; i < 16; ++i) { a += s_n[i]; c += s_c[i]; }
        PU u; u.f = make_float2(a, c);
        atomicExch(&part[blk], u.u);
        __threadfence();
        atomicExch(&flags[blk], TAG);
    }

    if (blk == 0) {
        if (t < NBLK) {
            while (atomicAdd(&flags[t], 0u) != TAG) __builtin_amdgcn_s_sleep(8);
        }
        __syncthreads();
        __threadfence();
        float a = 0.0f, c = 0.0f;
        if (t < NBLK) {                              // waves 0..3, whole waves uniform
            PU u; u.u = atomicAdd(&part[t], 0ull);
            a = wave_reduce(u.f.x);
            c = wave_reduce(u.f.y);
            if (lane == 0) { ra[wid] = a; rc[wid] = c; }
        }
        __syncthreads();
        if (t == 0) {
            float sn_ = ra[0] + ra[1] + ra[2] + ra[3];
            float sc_ = rc[0] + rc[1] + rc[2] + rc[3];
            out[0] = sn_ * (1.0f / NQ) + att_loss[0];   // LAMBDA = 1.0
            out[1] = sc_ * (1.0f / NQ);
        }
    }
}

extern "C" void kernel_launch(void* const* d_in, const int* in_sizes, int n_in,
                              void* d_out, int out_size, void* d_ws, size_t ws_size,
                              hipStream_t stream) {
    const float* out_f    = (const float*)d_in[0];
    // d_in[1] = labels_support (unused by reference)
    const int*   labels_q = (const int*)d_in[2];
    const float* att_loss = (const float*)d_in[3];
    // d_in[4] = mode (unused)
    float* out = (float*)d_out;

    ull*      part  = (ull*)d_ws;                   // 256 x 8 B
    unsigned* flags = (unsigned*)(part + NBLK);     // 256 x 4 B

    k_all<<<NBLK, 1024, 0, stream>>>(out_f, labels_q, att_loss, part, flags, out);
}

// Round 8
// 28.489 us; speedup vs baseline: 1.1407x; 1.1407x over previous
//
#include <hip/hip_runtime.h>

// Problem constants
#define B_       128
#define N_WAY    5
#define QUERY    15
#define NUM_SLOT 32
#define H_       256
#define NS       (B_ * N_WAY)            // 640 support samples
#define NQ       (B_ * N_WAY * QUERY)    // 9600 query samples
#define ROW      (NUM_SLOT * H_)         // 8192 floats per sample
#define SPB      (N_WAY * QUERY)         // 75 query samples per batch
#define RPB      (N_WAY * NUM_SLOT)      // 160 support rows per batch
#define NROWS    (NS * NUM_SLOT)         // 20480 support score rows
#define NBLK     (2 * B_)                // 256 blocks for K2, 2 per batch

__device__ __forceinline__ float wave_reduce(float v) {
    for (int m = 32; m > 0; m >>= 1) v += __shfl_xor(v, m, 64);
    return v;
}

// K1: full-chip streaming scores pass, NO redundancy. 256 blocks x 16 waves,
// 80 rows per block (5 per wave), 2-deep ILP on the row loop.
__global__ __launch_bounds__(1024)
void k_scores(const float* __restrict__ out_f, float* __restrict__ scores_g) {
    int t = threadIdx.x, wid = t >> 6, lane = t & 63;
    const float* base = out_f + (size_t)blockIdx.x * 80 * H_;
    float* og = scores_g + (size_t)blockIdx.x * 80;
    // rows wid, wid+16 | wid+32, wid+48 | wid+64  (5 rows per wave, 80 total)
    #pragma unroll
    for (int i = wid; i + 16 < 80; i += 32) {
        float4 v0 = ((const float4*)(base + (size_t)i * H_))[lane];
        float4 v1 = ((const float4*)(base + (size_t)(i + 16) * H_))[lane];
        float s0 = wave_reduce(v0.x + v0.y + v0.z + v0.w);
        float s1 = wave_reduce(v1.x + v1.y + v1.z + v1.w);
        if (lane == 0) { og[i] = s0 * (1.0f / H_); og[i + 16] = s1 * (1.0f / H_); }
    }
    {
        int i = wid + 64;
        float4 v = ((const float4*)(base + (size_t)i * H_))[lane];
        float s = wave_reduce(v.x + v.y + v.z + v.w);
        if (lane == 0) og[i] = s * (1.0f / H_);
    }
}

// K2: 2 blocks per batch, 16 waves each (full chip).
//  a) load the batch's 160 precomputed scores into LDS (640 B, not 160 KB)
//  b) wave-parallel butterfly greedy select (max, min-idx == stable first-max;
//     verified bit-exact in R7)
//  c) waves 0-4 normalize selected rows into LDS protos (+ exact p2; rows L3-hot)
//  d) each wave: its share of the block's 38/37 query samples; joint s2/dt
//     shuffle reduce (identical tree/bits to R5/R6), softmax-CE + argmin
//  e) one deterministic float2 partial per block
__global__ __launch_bounds__(1024)
void k_fused(const float* __restrict__ out_f, const float* __restrict__ scores_g,
             const int* __restrict__ labels_q, float2* __restrict__ part) {
    int blk = blockIdx.x, b = blk >> 1, half = blk & 1;
    int t = threadIdx.x, wid = t >> 6, lane = t & 63;

    __shared__ float sc[RPB];
    __shared__ int ssel[N_WAY];
    __shared__ __align__(16) float pl[N_WAY][H_];   // normalized protos (5 KB)
    __shared__ float p2s[N_WAY];
    __shared__ float s_n[16], s_c[16];

    // a) stage precomputed scores
    if (t < RPB) sc[t] = scores_g[(size_t)b * RPB + t];
    __syncthreads();

    // b) greedy select, wave-parallel: butterfly (max, min-index) == first-max scan
    if (t < 64) {
        unsigned used = 0u;
        for (int j = 0; j < N_WAY; ++j) {
            float v = (lane < NUM_SLOT && !((used >> lane) & 1u))
                        ? sc[j * NUM_SLOT + lane] : -INFINITY;
            int idx = (lane < NUM_SLOT) ? lane : 63;
            for (int m = 32; m > 0; m >>= 1) {
                float v2 = __shfl_xor(v, m, 64);
                int  i2 = __shfl_xor(idx, m, 64);
                if (v2 > v || (v2 == v && i2 < idx)) { v = v2; idx = i2; }
            }
            used |= 1u << idx;                       // all lanes converged
            if (lane == 0) ssel[j] = idx;
        }
    }
    __syncthreads();

    // c) normalize selected rows -> LDS protos; p2 via same reduce tree
    const float* base = out_f + (size_t)b * RPB * H_;
    if (wid < N_WAY) {
        int k = wid;
        float4 v = ((const float4*)(base + ((size_t)k * NUM_SLOT + ssel[k]) * H_))[lane];
        float s2 = wave_reduce(v.x*v.x + v.y*v.y + v.z*v.z + v.w*v.w);
        float inv = 1.0f / fmaxf(sqrtf(s2), 1e-12f);
        float4 nv = make_float4(v.x*inv, v.y*inv, v.z*inv, v.w*inv);
        *(float4*)&pl[k][lane * 4] = nv;
        float p2 = wave_reduce(nv.x*nv.x + nv.y*nv.y + nv.z*nv.z + nv.w*nv.w);
        if (lane == 0) p2s[k] = p2;
    }
    __syncthreads();

    // d) query samples: half 0 -> [0,38), half 1 -> [38,75)
    int sBeg = half ? 38 : 0;
    int sEnd = half ? SPB : 38;
    float accn = 0.0f, accc = 0.0f;
    for (int s = sBeg + wid; s < sEnd; s += 16) {
        int id = b * SPB + s;
        const float* qrow = out_f + (size_t)(NS + id) * ROW;
        float4 qv[N_WAY];
        #pragma unroll
        for (int k = 0; k < N_WAY; ++k)             // issue all 5 loads up front
            qv[k] = ((const float4*)(qrow + (size_t)ssel[k] * H_))[lane];
        float diffs[N_WAY];
        #pragma unroll
        for (int k = 0; k < N_WAY; ++k) {
            float4 pv = *(const float4*)&pl[k][lane * 4];
            float s2 = qv[k].x*qv[k].x + qv[k].y*qv[k].y + qv[k].z*qv[k].z + qv[k].w*qv[k].w;
            float dt = qv[k].x*pv.x + qv[k].y*pv.y + qv[k].z*pv.z + qv[k].w*pv.w;
            for (int m = 32; m > 0; m >>= 1) {
                s2 += __shfl_xor(s2, m, 64);
                dt += __shfl_xor(dt, m, 64);
            }
            float inv = 1.0f / fmaxf(sqrtf(s2), 1e-12f);
            diffs[k] = s2 * inv * inv - 2.0f * dt * inv + p2s[k];
        }
        if (lane == 0) {
            int l = labels_q[id];                   // label index == flat sample index
            float mn = diffs[0]; int am = 0;
            #pragma unroll
            for (int k = 1; k < N_WAY; ++k)
                if (diffs[k] < mn) { mn = diffs[k]; am = k; }  // first min == argmax logits
            float se = 0.0f;
            #pragma unroll
            for (int k = 0; k < N_WAY; ++k) se += expf(mn - diffs[k]);
            accn += diffs[l] - mn + logf(se);
            accc += (am == l) ? 1.0f : 0.0f;
        }
    }
    if (lane == 0) { s_n[wid] = accn; s_c[wid] = accc; }
    __syncthreads();

    // e) deterministic per-block partial
    if (t == 0) {
        float a = 0.0f, c = 0.0f;
        #pragma unroll
        for (int i = 0; i < 16; ++i) { a += s_n[i]; c += s_c[i]; }
        part[blk] = make_float2(a, c);
    }
}

// K3: deterministic fixed-order reduction of 256 float2 partials -> (loss, acc)
__global__ __launch_bounds__(256)
void k_finalize(const float2* __restrict__ part, const float* __restrict__ att_loss,
                float* __restrict__ out) {
    __shared__ float sa[4], sb[4];
    int t = threadIdx.x, wid = t >> 6, lane = t & 63;
    float2 p = part[t];                             // exactly 256 partials
    float a = wave_reduce(p.x);
    float c = wave_reduce(p.y);
    if (lane == 0) { sa[wid] = a; sb[wid] = c; }
    __syncthreads();
    if (t == 0) {
        float sn_ = sa[0] + sa[1] + sa[2] + sa[3];
        float sc_ = sb[0] + sb[1] + sb[2] + sb[3];
        out[0] = sn_ * (1.0f / NQ) + att_loss[0];   // LAMBDA = 1.0
        out[1] = sc_ * (1.0f / NQ);
    }
}

extern "C" void kernel_launch(void* const* d_in, const int* in_sizes, int n_in,
                              void* d_out, int out_size, void* d_ws, size_t ws_size,
                              hipStream_t stream) {
    const float* out_f    = (const float*)d_in[0];
    // d_in[1] = labels_support (unused by reference)
    const int*   labels_q = (const int*)d_in[2];
    const float* att_loss = (const float*)d_in[3];
    // d_in[4] = mode (unused)
    float* out = (float*)d_out;

    float*  scores_g = (float*)d_ws;                    // 20480 floats
    float2* part     = (float2*)(scores_g + NROWS);     // 256 float2

    k_scores  <<<NROWS / 80, 1024, 0, stream>>>(out_f, scores_g);
    k_fused   <<<NBLK,       1024, 0, stream>>>(out_f, scores_g, labels_q, part);
    k_finalize<<<1,          256,  0, stream>>>(part, att_loss, out);
}